// Round 10
// baseline (876.657 us; speedup 1.0000x reference)
//
#include <hip/hip_runtime.h>
#include <hip/hip_bf16.h>

constexpr int TT = 512, BB = 2048, NOUT = 8;
constexpr size_t DSTRIDE = (size_t)BB * TT * 24;   // f16 elems per dir region

typedef __attribute__((ext_vector_type(8))) _Float16 f16x8;
typedef __attribute__((ext_vector_type(4))) float f32x4;
typedef __attribute__((ext_vector_type(2))) _Float16 f16x2;

// fast device math: v_exp_f32 / v_rcp_f32 (1-ulp approx, no div sequence)
__device__ __forceinline__ float sigm(float x) {
    float e = __builtin_amdgcn_exp2f(x * -1.4426950408889634f);
    return __builtin_amdgcn_rcpf(1.f + e);
}
__device__ __forceinline__ float tanh_(float x) {
    float e = __builtin_amdgcn_exp2f(x * 2.8853900817779268f);
    return __builtin_fmaf(-2.f, __builtin_amdgcn_rcpf(e + 1.f), 1.f);
}
// v_cvt_pkrtz_f16_f32 with a bit-cast to our f16x2 (builtin returns __fp16x2)
__device__ __forceinline__ f16x2 pkrtz(float a, float b) {
    auto p = __builtin_amdgcn_cvt_pkrtz(a, b);
    f16x2 r; __builtin_memcpy(&r, &p, 4); return r;
}
// TBAA-safe LDS load (char aliasing -> ordered w.r.t. any-type stores)
__device__ __forceinline__ f32x4 ldf4(const void* p) {
    f32x4 r; __builtin_memcpy(&r, p, 16); return r;
}
__device__ __forceinline__ void wbar() { __builtin_amdgcn_wave_barrier(); }

// R18: dot2-rate experiment / fix. VALUBusy arithmetic (67% = ~157 slots/step
// vs ~70 counted at full-rate) implies v_dot2_f32_f16 issues at ~1/4 rate on
// gfx950. Replace 36 fdot2 with 69 v_fmac_f32 (full-rate):
//  - W_hh rows (u, 23+u, 46+u) as f32 in 69 VGPRs
//  - h history f32 in LDS (rows of 32 f32; broadcast reads, conflict-free);
//    per-step cvt removed from the chain; f16 quantization moved to the
//    store phase (recurrence now fully f32 -> precision improves)
// LDS 79.2KB/block, still 2 blocks/CU (158.5 <= 160KiB). launch_bounds(256,2)
// pins VGPR<=256. Schedule = R13/R17 (best measured) unchanged.
template <bool L0, bool LAST>
__global__ __launch_bounds__(256, 2) void gru_mfma(
    const void* __restrict__ in_,        // L0: x [B][T][32] f32; else region0 (region1 at +DSTRIDE)
    const float* __restrict__ fmean, const float* __restrict__ fstd,
    const float* __restrict__ wih_g, const float* __restrict__ whh_g,
    const float* __restrict__ bih_g, const float* __restrict__ bhh_g,
    unsigned short* __restrict__ outbuf, float* __restrict__ lastbuf)
{
    constexpr int KIN = L0 ? 32 : 46;
    constexpr int KF  = L0 ? 1 : 2;
    constexpr int DSTR = 20;             // D-tile row stride (f32), 80B

    // [tile t<5][kslot<8][lane m<16][8 halves] staging for B-frags
    __shared__ __align__(16) _Float16  wih_lds[5 * 8 * 16 * 8];
    __shared__ __align__(16) float     whh_f[80 * 24];        // W_hh f32
    __shared__ __align__(16) float     xg_s[4][2][80 * DSTR]; // per-wave D dbuf
    __shared__ __align__(16) float     hist_f[4 * 9 * 2 * 32];  // h history f32
    __shared__ float bih_s[80], bhh_s[80];
    __shared__ __align__(16) float an_s[32], cn_s[32];

    const int tid = threadIdx.x, wv = tid >> 6, lane = tid & 63;
    const int bl = lane >> 5, u = lane & 31;
    const int m  = lane & 15, kg = lane >> 4;             // MFMA lane coords
    const int dir = blockIdx.y;
    const int bg  = blockIdx.x * 8 + wv * 2 + bl;

    const float* wih_d = wih_g + dir * 69 * KIN;
    const float* whh_d = whh_g + dir * 69 * 23;

    // ---- stage W_ih frags [t][kslot][m][8], col-remapped, zero-padded ----
    for (int idx = tid; idx < 5120; idx += 256) {
        int t = idx >> 10, r = idx & 1023;
        int kslot = r >> 7, mm = (r >> 3) & 15, j = r & 7;
        int row = t * 16 + mm, k = kslot * 8 + j;
        float v = 0.f;
        if (row < 69) {
            if constexpr (L0) {
                if (k < 32) v = wih_d[row * 32 + k];
            } else {
                if (k < 23) v = wih_d[row * 46 + k];                      // fwd
                else if (k >= 24 && k < 47) v = wih_d[row * 46 + k - 1];  // bwd
            }
        }
        wih_lds[idx] = (_Float16)v;
    }
    for (int idx = tid; idx < 80 * 24; idx += 256) {
        int j = idx / 24, k = idx - j * 24;
        whh_f[idx] = (j < 69 && k < 23) ? whh_d[j * 23 + k] : 0.f;
    }
    for (int idx = tid; idx < 80; idx += 256) {
        bih_s[idx] = (idx < 69) ? bih_g[dir * 69 + idx] : 0.f;
        bhh_s[idx] = (idx < 69) ? bhh_g[dir * 69 + idx] : 0.f;
    }
    for (int idx = tid; idx < 4 * 9 * 2 * 32; idx += 256)
        hist_f[idx] = 0.f;
    if (L0 && tid < 32) {
        float sd = fstd[tid];
        float sa = (sd == 0.f) ? 1.f : sd;        // std==0 -> 1
        float a  = (sa == 1.f) ? 0.f : 1.f / sa;  // adjusted std==1 -> zero
        an_s[tid] = a;
        cn_s[tid] = -fmean[tid] * a;
    }
    __syncthreads();   // only block-wide barrier

    // ---- per-lane W_hh rows (u, 23+u, 46+u) as f32 -> 69 VGPRs ----
    float wrf[3][23];
    float bh2;
    #pragma unroll
    for (int r = 0; r < 3; ++r) {
        int row = r * 23 + u;   // <= 77 < 80
        #pragma unroll
        for (int k = 0; k < 23; ++k)
            wrf[r][k] = whh_f[row * 24 + k];
    }
    bh2 = bhh_s[46 + u];   // n-row b_hh stays inside r*(...)
    // D-tile bias: b_ih (+ b_hh for r/z rows, which add outside the r gate)
    float bi5[5];
    #pragma unroll
    for (int t = 0; t < 5; ++t) {
        int n = t * 16 + m;
        bi5[t] = bih_s[n] + (n < 46 ? bhh_s[n] : 0.f);
    }

    // ---- B-fragments register-resident ----
    const f16x8* bfrag = (const f16x8*)wih_lds;   // [t*8+kslot][m]
    f16x8 bfr[5][KF];
    #pragma unroll
    for (int t = 0; t < 5; ++t)
        #pragma unroll
        for (int kf = 0; kf < KF; ++kf)
            bfr[t][kf] = bfrag[(t * 8 + kf * 4 + kg) * 16 + m];

    float an8[L0 ? 8 : 1], cn8[L0 ? 8 : 1];
    if constexpr (L0) {
        #pragma unroll
        for (int j = 0; j < 8; ++j) {
            an8[j] = an_s[kg * 8 + j];
            cn8[j] = cn_s[kg * 8 + j];
        }
    }

    float* db0 = &xg_s[wv][0][0];
    float* db1 = &xg_s[wv][1][0];
    float* hw = &hist_f[wv * 9 * 2 * 32];
    const int ngroups = (LAST && dir == 1) ? 1 : 64;
    float hold = 0.f;

    // ---- store-phase lane constants (hoisted) ----
    int sarr[3], cparr[3], ldsoff[3];
    {
        int idx = lane & 31;
        #pragma unroll
        for (int c = 0; c < 3; ++c) {
            int p = idx + 32 * c;             // 0..95
            sarr[c]  = p / 12;
            cparr[c] = p - 12 * sarr[c];
            ldsoff[c] = ((sarr[c] + 1) * 2 + bl) * 32 + 2 * cparr[c];
        }
    }
    unsigned short* dstbase = nullptr;
    if constexpr (!LAST)
        dstbase = outbuf + dir * DSTRIDE + (size_t)bg * TT * 24;

    // A-row coords: m = bl_a*8 + tl
    const int bl_a = m >> 3, tl = m & 7;
    const int b_a  = blockIdx.x * 8 + wv * 2 + bl_a;

    const unsigned short* r0 = (const unsigned short*)in_;
    const unsigned short* r1 = r0 + DSTRIDE;

    float4 xraw0, xraw1;                 // L0 raw x
    f16x8 a0r, a1r;                      // !L0 f16 frags (a1r upper pre-masked)
    const f16x8 zz = {};

    // ---- load raw A data for group 0 ----
    {
        const int tg_a = dir ? (511 - tl) : tl;
        if constexpr (L0) {
            const float* xr = (const float*)in_ +
                              ((size_t)b_a * TT + tg_a) * 32 + kg * 8;
            xraw0 = *(const float4*)xr;
            xraw1 = *(const float4*)(xr + 4);
        } else {
            size_t rowoff = ((size_t)b_a * TT + tg_a) * 24;
            const unsigned short* p0 =
                (kg < 3) ? (r0 + rowoff + 8 * kg) : (r1 + rowoff);
            const unsigned short* p1 =
                (kg == 0) ? (r1 + rowoff + 8) : (r1 + rowoff + 16);
            __builtin_memcpy(&a0r, p0, 16);
            __builtin_memcpy(&a1r, p1, 16);
            if (kg >= 2) a1r = zz;
        }
    }

    // ---- prologue: MFMA for group 0 -> db0 (monolithic, once) ----
    {
        f32x4 acc0[5];
        #pragma unroll
        for (int t = 0; t < 5; ++t)
            acc0[t] = (f32x4){bi5[t], bi5[t], bi5[t], bi5[t]};
        if constexpr (L0) {
            float xv[8] = {xraw0.x, xraw0.y, xraw0.z, xraw0.w,
                           xraw1.x, xraw1.y, xraw1.z, xraw1.w};
            f16x8 afr0;
            #pragma unroll
            for (int j = 0; j < 4; ++j) {
                f16x2 p = pkrtz(xv[2 * j] * an8[2 * j] + cn8[2 * j],
                                xv[2 * j + 1] * an8[2 * j + 1] + cn8[2 * j + 1]);
                afr0[2 * j]     = p[0];
                afr0[2 * j + 1] = p[1];
            }
            #pragma unroll
            for (int t = 0; t < 5; ++t)
                acc0[t] = __builtin_amdgcn_mfma_f32_16x16x32_f16(afr0, bfr[t][0],
                                                                 acc0[t], 0, 0, 0);
        } else {
            #pragma unroll
            for (int t = 0; t < 5; ++t) {
                acc0[t] = __builtin_amdgcn_mfma_f32_16x16x32_f16(a0r, bfr[t][0],
                                                                 acc0[t], 0, 0, 0);
                acc0[t] = __builtin_amdgcn_mfma_f32_16x16x32_f16(a1r, bfr[t][1],
                                                                 acc0[t], 0, 0, 0);
            }
        }
        #pragma unroll
        for (int t = 0; t < 5; ++t)
            *(f32x4*)&db0[(t * 16 + m) * DSTR + kg * 4] = acc0[t];
    }
    // ---- load raw A data for group 1 ----
    if (1 < ngroups) {
        const int tg_a = dir ? (511 - (8 + tl)) : (8 + tl);
        if constexpr (L0) {
            const float* xr = (const float*)in_ +
                              ((size_t)b_a * TT + tg_a) * 32 + kg * 8;
            xraw0 = *(const float4*)xr;
            xraw1 = *(const float4*)(xr + 4);
        } else {
            size_t rowoff = ((size_t)b_a * TT + tg_a) * 24;
            const unsigned short* p0 =
                (kg < 3) ? (r0 + rowoff + 8 * kg) : (r1 + rowoff);
            const unsigned short* p1 =
                (kg == 0) ? (r1 + rowoff + 8) : (r1 + rowoff + 16);
            __builtin_memcpy(&a0r, p0, 16);
            __builtin_memcpy(&a1r, p1, 16);
            if (kg >= 2) a1r = zz;
        }
    }

    int cur = 0;
    f32x4 acc[5];
    f16x8 afr;

    // Group body; called with LITERAL domfma/doload -> main-loop instances
    // are branch-free after constant folding + inlining.
    auto group_body = [&](int g, bool domfma, bool doload) {
        float* Dc = cur ? db1 : db0;
        float* Dn = cur ? db0 : db1;
        wbar();   // D(cur) writes precede in program order (in-order DS)

        // ---- prefetch this group's xg: 2x b128 per gate row (col-major D) --
        float xgr[8][3];
        #pragma unroll
        for (int c = 0; c < 3; ++c) {
            const f32x4 lo = *(const f32x4*)&Dc[(c * 23 + u) * DSTR + bl * 8];
            const f32x4 hi = *(const f32x4*)&Dc[(c * 23 + u) * DSTR + bl * 8 + 4];
            #pragma unroll
            for (int s = 0; s < 8; ++s)
                xgr[s][c] = (s < 4) ? lo[s] : hi[s - 4];
        }

        // ---- 8 scan steps with next-group work interleaved ----
        #pragma unroll
        for (int s8 = 0; s8 < 8; ++s8) {
            const float* hr = &hw[(s8 * 2 + bl) * 32];   // prev h (f32)
            f32x4 hv0 = ldf4(hr);
            f32x4 hv1 = ldf4(hr + 4);
            f32x4 hv2 = ldf4(hr + 8);
            f32x4 hv3 = ldf4(hr + 12);
            f32x4 hv4 = ldf4(hr + 16);
            f32x4 hv5 = ldf4(hr + 20);

            // ---- filler: independent work under hist-read latency ----
            if (s8 <= 4) {
                if (domfma) {
                    if constexpr (L0) {
                        if (s8 == 0) {
                            float xv[8] = {xraw0.x, xraw0.y, xraw0.z, xraw0.w,
                                           xraw1.x, xraw1.y, xraw1.z, xraw1.w};
                            #pragma unroll
                            for (int j = 0; j < 4; ++j) {
                                f16x2 p = pkrtz(
                                    xv[2 * j] * an8[2 * j] + cn8[2 * j],
                                    xv[2 * j + 1] * an8[2 * j + 1] + cn8[2 * j + 1]);
                                afr[2 * j]     = p[0];
                                afr[2 * j + 1] = p[1];
                            }
                        }
                        acc[s8] = (f32x4){bi5[s8], bi5[s8], bi5[s8], bi5[s8]};
                        acc[s8] = __builtin_amdgcn_mfma_f32_16x16x32_f16(
                            afr, bfr[s8][0], acc[s8], 0, 0, 0);
                    } else {
                        acc[s8] = (f32x4){bi5[s8], bi5[s8], bi5[s8], bi5[s8]};
                        acc[s8] = __builtin_amdgcn_mfma_f32_16x16x32_f16(
                            a0r, bfr[s8][0], acc[s8], 0, 0, 0);
                        acc[s8] = __builtin_amdgcn_mfma_f32_16x16x32_f16(
                            a1r, bfr[s8][1], acc[s8], 0, 0, 0);
                    }
                    if (s8 >= 1)
                        *(f32x4*)&Dn[((s8 - 1) * 16 + m) * DSTR + kg * 4] =
                            acc[s8 - 1];
                }
            } else if (s8 == 5) {
                if (domfma)
                    *(f32x4*)&Dn[(4 * 16 + m) * DSTR + kg * 4] = acc[4];
            } else if (s8 == 6) {
                if (doload) {
                    const int tg_n = dir ? (511 - ((g + 2) * 8 + tl))
                                         : ((g + 2) * 8 + tl);
                    if constexpr (L0) {
                        const float* xr = (const float*)in_ +
                                          ((size_t)b_a * TT + tg_n) * 32 + kg * 8;
                        xraw0 = *(const float4*)xr;
                        xraw1 = *(const float4*)(xr + 4);
                    } else {
                        size_t rowoff = ((size_t)b_a * TT + tg_n) * 24;
                        const unsigned short* p0 =
                            (kg < 3) ? (r0 + rowoff + 8 * kg) : (r1 + rowoff);
                        const unsigned short* p1 =
                            (kg == 0) ? (r1 + rowoff + 8) : (r1 + rowoff + 16);
                        __builtin_memcpy(&a0r, p0, 16);
                        __builtin_memcpy(&a1r, p1, 16);
                        if (kg >= 2) a1r = zz;
                    }
                }
            }

            // ---- dots via full-rate v_fmac_f32 (dual accumulators) ----
            float hh[24];
            #pragma unroll
            for (int q = 0; q < 4; ++q) {
                hh[q]      = hv0[q];
                hh[4 + q]  = hv1[q];
                hh[8 + q]  = hv2[q];
                hh[12 + q] = hv3[q];
                hh[16 + q] = hv4[q];
                hh[20 + q] = hv5[q];
            }
            float a0a = xgr[s8][0], a1a = xgr[s8][1], a2a = bh2;
            float a0b = 0.f, a1b = 0.f, a2b = 0.f;
            #pragma unroll
            for (int k = 0; k < 12; ++k) {
                a0a = __builtin_fmaf(wrf[0][k], hh[k], a0a);
                a1a = __builtin_fmaf(wrf[1][k], hh[k], a1a);
                a2a = __builtin_fmaf(wrf[2][k], hh[k], a2a);
            }
            #pragma unroll
            for (int k = 12; k < 23; ++k) {
                a0b = __builtin_fmaf(wrf[0][k], hh[k], a0b);
                a1b = __builtin_fmaf(wrf[1][k], hh[k], a1b);
                a2b = __builtin_fmaf(wrf[2][k], hh[k], a2b);
            }
            float r_ = sigm(a0a + a0b);
            float z_ = sigm(a1a + a1b);
            float n_ = tanh_(__builtin_fmaf(r_, a2a + a2b, xgr[s8][2]));
            float hnew = n_ + z_ * (hold - n_);
            hold = hnew;
            if constexpr (LAST) {
                int tg = dir ? (511 - (g * 8 + s8)) : (g * 8 + s8);
                if (u < 23 && tg == TT - 1)
                    lastbuf[bg * 48 + dir * 23 + u] = hnew;
            }
            hw[((s8 + 1) * 2 + bl) * 32 + u] = hnew;  // f32, pads in 23..31
        }

        wbar();   // steps' hist writes precede store-phase reads

        // ---- cooperative coalesced store: quantize f32 pair -> f16 word ----
        if constexpr (!LAST) {
            #pragma unroll
            for (int c = 0; c < 3; ++c) {
                float pr[2];
                __builtin_memcpy(pr, &hw[ldsoff[c]], 8);
                float hi = (cparr[c] == 11) ? 0.f : pr[1];   // col 23 := 0
                f16x2 pk = pkrtz(pr[0], hi);
                unsigned w; __builtin_memcpy(&w, &pk, 4);
                int tg = dir ? (511 - (g * 8 + sarr[c])) : (g * 8 + sarr[c]);
                *(unsigned*)(dstbase + (size_t)tg * 24 + 2 * cparr[c]) = w;
            }
        }
        // carry h into row 0 for next group (disjoint from store-phase rows)
        hw[bl * 32 + u] = hold;
        wbar();
        cur ^= 1;
    };

    // main loop: 62/64 groups with literal-true flags -> branch-free body
    for (int g = 0; g + 2 < ngroups; ++g)
        group_body(g, true, true);
    if (ngroups >= 2)
        group_body(ngroups - 2, true, false);
    group_body(ngroups - 1, false, false);
}

__global__ __launch_bounds__(256) void fc_kernel(
    const float* __restrict__ last, const float* __restrict__ fcw,
    const float* __restrict__ fcb, const float* __restrict__ ostd,
    const float* __restrict__ omean, float* __restrict__ out)
{
    int idx = blockIdx.x * 256 + threadIdx.x;
    if (idx >= BB * NOUT) return;
    int b = idx >> 3, o = idx & 7;
    float acc = fcb[o];
    const float* lr = last + b * 48;
    const float* wr = fcw + o * 46;
    #pragma unroll
    for (int i = 0; i < 46; i++) acc += lr[i] * wr[i];
    out[idx] = acc * ostd[o] + omean[o];
}

extern "C" void kernel_launch(void* const* d_in, const int* in_sizes, int n_in,
                              void* d_out, int out_size, void* d_ws,
                              size_t ws_size, hipStream_t stream)
{
    const float* x     = (const float*)d_in[0];
    const float* fmean = (const float*)d_in[1];
    const float* fstd  = (const float*)d_in[2];
    const float* omean = (const float*)d_in[3];
    const float* ostd  = (const float*)d_in[4];
    const float* wih0  = (const float*)d_in[5];
    const float* whh0  = (const float*)d_in[6];
    const float* bih0  = (const float*)d_in[7];
    const float* bhh0  = (const float*)d_in[8];
    const float* wihr  = (const float*)d_in[9];
    const float* whhr  = (const float*)d_in[10];
    const float* bihr  = (const float*)d_in[11];
    const float* bhhr  = (const float*)d_in[12];
    const float* fcw   = (const float*)d_in[13];
    const float* fcb   = (const float*)d_in[14];

    char* ws = (char*)d_ws;
    const size_t bufBytes = 2 * DSTRIDE * sizeof(unsigned short);  // 96 MiB
    unsigned short* buf0 = (unsigned short*)ws;
    unsigned short* buf1 = (unsigned short*)(ws + bufBytes);
    float* lastb         = (float*)(ws + 2 * bufBytes);

    dim3 grid(BB / 8, 2);

    gru_mfma<true, false><<<grid, 256, 0, stream>>>(
        x, fmean, fstd, wih0, whh0, bih0, bhh0, buf0, nullptr);
    gru_mfma<false, false><<<grid, 256, 0, stream>>>(
        buf0, nullptr, nullptr, wihr + 0 * 2 * 69 * 46, whhr + 0 * 2 * 69 * 23,
        bihr + 0 * 2 * 69, bhhr + 0 * 2 * 69, buf1, nullptr);
    gru_mfma<false, true><<<grid, 256, 0, stream>>>(
        buf1, nullptr, nullptr, wihr + 1 * 2 * 69 * 46, whhr + 1 * 2 * 69 * 23,
        bihr + 1 * 2 * 69, bhhr + 1 * 2 * 69, nullptr, lastb);
    fc_kernel<<<(BB * NOUT + 255) / 256, 256, 0, stream>>>(lastb, fcw, fcb, ostd,
                                                           omean, (float*)d_out);
}